// Round 6
// baseline (914.858 us; speedup 1.0000x reference)
//
#include <hip/hip_runtime.h>
#include <hip/hip_bf16.h>

#define BN_EPS 1e-5f
#define BINSHIFT 6
#define BINW 64
#define NBLK 256   // chunks for the contention-free counting sort

// ===========================================================================
// Preprocessing: contention-free counting sort of edges by bin = dst>>6.
// (hist2d / colsum / bin_scan / rowscan / place unchanged from round 5.)
// Edges only need to be grouped by bin now — no per-node fine sort.
// ===========================================================================

__global__ __launch_bounds__(256)
void hist2d_kernel(const int* __restrict__ dst, int* __restrict__ histmat,
                   int E, int nbins, int chunk) {
    __shared__ int h[2048];
    for (int i = threadIdx.x; i < nbins; i += 256) h[i] = 0;
    __syncthreads();
    int b = blockIdx.x;
    int e0 = b * chunk;
    int e1 = min(E, e0 + chunk);
    for (int e = e0 + threadIdx.x; e < e1; e += 256)
        atomicAdd(&h[dst[e] >> BINSHIFT], 1);
    __syncthreads();
    int* row = histmat + (size_t)b * nbins;
    for (int i = threadIdx.x; i < nbins; i += 256) row[i] = h[i];
}

__global__ __launch_bounds__(256)
void colsum_kernel(const int* __restrict__ histmat, int* __restrict__ bincnt,
                   int nbins) {
    int bin = blockIdx.x * 256 + threadIdx.x;
    if (bin >= nbins) return;
    int s = 0;
    for (int r = 0; r < NBLK; ++r) s += histmat[(size_t)r * nbins + bin];
    bincnt[bin] = s;
}

__global__ __launch_bounds__(1024)
void bin_scan_kernel(const int* __restrict__ bincnt, int* __restrict__ binstart,
                     int nbins, int E) {
    __shared__ int a[2048];
    __shared__ int b[1024];
    int t = threadIdx.x;
    a[t]        = (t < nbins) ? bincnt[t] : 0;
    a[t + 1024] = (t + 1024 < nbins) ? bincnt[t + 1024] : 0;
    __syncthreads();
    b[t] = a[2 * t] + a[2 * t + 1];
    __syncthreads();
    for (int off = 1; off < 1024; off <<= 1) {
        int v = (t >= off) ? b[t - off] : 0;
        __syncthreads();
        b[t] += v;
        __syncthreads();
    }
    int base = (t == 0) ? 0 : b[t - 1];
    if (2 * t < nbins)     binstart[2 * t]     = base;
    if (2 * t + 1 < nbins) binstart[2 * t + 1] = base + a[2 * t];
    if (t == 0) binstart[nbins] = E;
}

__global__ __launch_bounds__(256)
void rowscan_kernel(int* __restrict__ histmat, const int* __restrict__ binstart,
                    int nbins) {
    __shared__ int a[NBLK];
    int b = blockIdx.x;
    int t = threadIdx.x;
    int v = histmat[(size_t)t * nbins + b];
    a[t] = v;
    __syncthreads();
    for (int off = 1; off < NBLK; off <<= 1) {
        int add = (t >= off) ? a[t - off] : 0;
        __syncthreads();
        a[t] += add;
        __syncthreads();
    }
    histmat[(size_t)t * nbins + b] = binstart[b] + a[t] - v;
}

__global__ __launch_bounds__(256)
void place_kernel(const int* __restrict__ src, const int* __restrict__ dst,
                  const int* __restrict__ histmat, int2* __restrict__ tmp_meta,
                  int E, int nbins, int chunk) {
    __shared__ int cur[2048];
    int b = blockIdx.x;
    const int* row = histmat + (size_t)b * nbins;
    for (int i = threadIdx.x; i < nbins; i += 256) cur[i] = row[i];
    __syncthreads();
    int e0 = b * chunk;
    int e1 = min(E, e0 + chunk);
    for (int e = e0 + threadIdx.x; e < e1; e += 256) {
        int d = dst[e];
        int bin = d >> BINSHIFT;
        int pos = atomicAdd(&cur[bin], 1);   // LDS atomic
        int2 m;
        m.x = ((d & (BINW - 1)) << 20) | src[e];  // src < 2^20
        m.y = e;
        tmp_meta[pos] = m;
    }
}

// Streaming ea permute into bin-grouped order (replaces old pass2).
__global__ __launch_bounds__(256)
void permute_ea_kernel(const float* __restrict__ edge_attr,
                       const int2* __restrict__ tmp_meta,
                       float* __restrict__ ea_sorted, int E) {
    int e = blockIdx.x * 256 + threadIdx.x;
    if (e >= E) return;
    int eid = tmp_meta[e].y;
    const float4* sp = (const float4*)(edge_attr + (size_t)eid * 8);
    float4 a0 = sp[0], a1 = sp[1];
    float4* dp = (float4*)(ea_sorted + (size_t)e * 8);
    dp[0] = a0;
    dp[1] = a1;
}

// ===========================================================================
// Fused GINE layer, EDGE-PARALLEL per bin: one block per bin (64 nodes).
// Edges processed wave-parallel (LPN lanes/edge, unroll-2 for MLP latency);
// messages accumulated with LDS float atomics into padded s_agg. Then the
// node transform (Linear1+BN+ReLU, Linear2+ReLU) runs on the bin's 64 nodes.
// No degree divergence, no dependent serial load chain, no global atomics.
// ===========================================================================
template<int DIN, int LPN>
__global__ __launch_bounds__(256)
void gine_layer_bin(const float* __restrict__ xin,      // [N, DIN]
                    const int*   __restrict__ binstart, // [nbins+1]
                    const int2*  __restrict__ tmp_meta, // [E] (dl<<20|src, eid)
                    const float* __restrict__ ea_sorted,// [E, 8]
                    const float* __restrict__ ew, const float* __restrict__ eb,
                    const float* __restrict__ wa, const float* __restrict__ ba,
                    const float* __restrict__ g, const float* __restrict__ be,
                    const float* __restrict__ m, const float* __restrict__ v,
                    const float* __restrict__ wb, const float* __restrict__ bb,
                    float* __restrict__ hout,           // [N, 16]
                    int N) {
    static_assert(DIN / LPN == 4, "4 channels per lane");
    constexpr int EPB = 256 / LPN;      // edges per block-iteration
    constexpr int PAD = DIN + 1;

    __shared__ float s_agg[BINW * PAD];
    __shared__ float s_wa[DIN * 16];
    __shared__ float s_wb[16 * 16];
    __shared__ float s_ba[16], s_scale[16], s_shift[16], s_bb[16];
    __shared__ float s_h[BINW * 17];

    int t = threadIdx.x;
    // stage weights + zero accumulator
    for (int idx = t; idx < BINW * PAD; idx += 256) s_agg[idx] = 0.f;
    for (int idx = t; idx < DIN * 16; idx += 256) s_wa[idx] = wa[idx];
    s_wb[t] = wb[t];
    if (t < 16) {
        s_ba[t] = ba[t];
        float sc = g[t] * rsqrtf(v[t] + BN_EPS);
        s_scale[t] = sc;
        s_shift[t] = be[t] - m[t] * sc;
        s_bb[t] = bb[t];
    }

    int group = t / LPN;      // edge slot within iteration
    int lane  = t % LPN;      // channel group
    int c0    = lane * 4;

    // hoist this lane's ew columns + eb
    float ew_r[8][4];
#pragma unroll
    for (int k = 0; k < 8; ++k) {
        float4 w = *(const float4*)(ew + k * DIN + c0);
        ew_r[k][0] = w.x; ew_r[k][1] = w.y; ew_r[k][2] = w.z; ew_r[k][3] = w.w;
    }
    float4 ebv = *(const float4*)(eb + c0);
    float eb_r[4] = {ebv.x, ebv.y, ebv.z, ebv.w};

    int b = blockIdx.x;
    int node0 = b << BINSHIFT;
    int e0 = binstart[b], e1 = binstart[b + 1];
    __syncthreads();

    // ---- edge phase: unroll-2, clamped loads, predicated LDS atomics ----
    for (int base = e0; base < e1; base += 2 * EPB) {
        int eA = base + group;
        int eB = eA + EPB;
        int cA = min(eA, e1 - 1);
        int cB = min(eB, e1 - 1);

        int2 mA = tmp_meta[cA];
        int2 mB = tmp_meta[cB];
        const float4* pA = (const float4*)(ea_sorted + (size_t)cA * 8);
        const float4* pB = (const float4*)(ea_sorted + (size_t)cB * 8);
        float4 a0A = pA[0], a1A = pA[1];
        float4 a0B = pB[0], a1B = pB[1];

        int sA = mA.x & 0xFFFFF, dlA = mA.x >> 20;
        int sB = mB.x & 0xFFFFF, dlB = mB.x >> 20;
        float4 xA = *(const float4*)(xin + (size_t)sA * DIN + c0);
        float4 xB = *(const float4*)(xin + (size_t)sB * DIN + c0);

        float avA[8] = {a0A.x, a0A.y, a0A.z, a0A.w, a1A.x, a1A.y, a1A.z, a1A.w};
        float avB[8] = {a0B.x, a0B.y, a0B.z, a0B.w, a1B.x, a1B.y, a1B.z, a1B.w};
        float xrA[4] = {xA.x, xA.y, xA.z, xA.w};
        float xrB[4] = {xB.x, xB.y, xB.z, xB.w};

        float msgA[4], msgB[4];
#pragma unroll
        for (int j = 0; j < 4; ++j) {
            float la = eb_r[j], lb = eb_r[j];
#pragma unroll
            for (int k = 0; k < 8; ++k) {
                la = fmaf(avA[k], ew_r[k][j], la);
                lb = fmaf(avB[k], ew_r[k][j], lb);
            }
            la += xrA[j];
            lb += xrB[j];
            msgA[j] = la > 0.f ? la : 0.f;
            msgB[j] = lb > 0.f ? lb : 0.f;
        }
        if (eA < e1) {
#pragma unroll
            for (int j = 0; j < 4; ++j)
                atomicAdd(&s_agg[dlA * PAD + c0 + j], msgA[j]);
        }
        if (eB < e1) {
#pragma unroll
            for (int j = 0; j < 4; ++j)
                atomicAdd(&s_agg[dlB * PAD + c0 + j], msgB[j]);
        }
    }
    __syncthreads();

    // ---- node transform: 4 threads per node ----
    int nl = t >> 2;          // node within bin
    int l  = t & 3;
    int i  = node0 + nl;
    constexpr int CPT = DIN / 4;   // channels per thread for the x-add

    if (i < N) {
        // s_agg[nl][*] += x_i
#pragma unroll
        for (int q = 0; q < CPT / 4; ++q) {
            float4 xv = *(const float4*)(xin + (size_t)i * DIN + l * CPT + q * 4);
            s_agg[nl * PAD + l * CPT + q * 4 + 0] += xv.x;
            s_agg[nl * PAD + l * CPT + q * 4 + 1] += xv.y;
            s_agg[nl * PAD + l * CPT + q * 4 + 2] += xv.z;
            s_agg[nl * PAD + l * CPT + q * 4 + 3] += xv.w;
        }
    }
    __syncthreads();

    if (i < N) {
#pragma unroll
        for (int o = 0; o < 4; ++o) {
            int j = l * 4 + o;
            float a = s_ba[j];
#pragma unroll
            for (int k = 0; k < DIN; ++k)
                a = fmaf(s_agg[nl * PAD + k], s_wa[k * 16 + j], a);
            a = a * s_scale[j] + s_shift[j];
            s_h[nl * 17 + j] = a > 0.f ? a : 0.f;
        }
    }
    __syncthreads();

    if (i < N) {
        float o_[4];
#pragma unroll
        for (int o = 0; o < 4; ++o) {
            int j = l * 4 + o;
            float a = s_bb[j];
#pragma unroll
            for (int k = 0; k < 16; ++k)
                a = fmaf(s_h[nl * 17 + k], s_wb[k * 16 + j], a);
            o_[o] = a > 0.f ? a : 0.f;
        }
        float4 ov = {o_[0], o_[1], o_[2], o_[3]};
        *(float4*)(hout + (size_t)i * 16 + l * 4) = ov;
    }
}

// ===========================================================================
// Head (unchanged)
// ===========================================================================
__global__ __launch_bounds__(256)
void final_kernel(const float* __restrict__ h1, const float* __restrict__ h2,
                  const float* __restrict__ h3,
                  const float* __restrict__ lw1, const float* __restrict__ lb1,
                  const float* __restrict__ lw2, const float* __restrict__ lb2,
                  float* __restrict__ out, int N) {
    constexpr int NPB = 64;
    __shared__ float s_lw1[48 * 64];
    __shared__ float s_lw2[64 * 4];
    __shared__ float s_lb1[64];
    __shared__ float s_lb2[4];
    __shared__ float s_c[NPB][49];

    int t = threadIdx.x;
    for (int idx = t; idx < 48 * 64; idx += 256) s_lw1[idx] = lw1[idx];
    s_lw2[t] = lw2[t];
    if (t < 64) s_lb1[t] = lb1[t];
    if (t < 4) s_lb2[t] = lb2[t];

    int nl = t >> 2;
    int l  = t & 3;
    int i  = blockIdx.x * NPB + nl;

    if (i < N) {
        float4 c1 = ((const float4*)(h1 + (size_t)i * 16))[l];
        float4 c2 = ((const float4*)(h2 + (size_t)i * 16))[l];
        float4 c3 = ((const float4*)(h3 + (size_t)i * 16))[l];
        s_c[nl][l * 4 + 0] = c1.x; s_c[nl][l * 4 + 1] = c1.y;
        s_c[nl][l * 4 + 2] = c1.z; s_c[nl][l * 4 + 3] = c1.w;
        s_c[nl][16 + l * 4 + 0] = c2.x; s_c[nl][16 + l * 4 + 1] = c2.y;
        s_c[nl][16 + l * 4 + 2] = c2.z; s_c[nl][16 + l * 4 + 3] = c2.w;
        s_c[nl][32 + l * 4 + 0] = c3.x; s_c[nl][32 + l * 4 + 1] = c3.y;
        s_c[nl][32 + l * 4 + 2] = c3.z; s_c[nl][32 + l * 4 + 3] = c3.w;
    }
    __syncthreads();

    float o0 = 0.f, o1 = 0.f, o2 = 0.f, o3 = 0.f;
    if (i < N) {
#pragma unroll 4
        for (int jj = 0; jj < 16; ++jj) {
            int j = l * 16 + jj;
            float a = s_lb1[j];
#pragma unroll
            for (int k = 0; k < 48; ++k) a = fmaf(s_c[nl][k], s_lw1[k * 64 + j], a);
            a = a > 0.f ? a : 0.f;
            o0 = fmaf(a, s_lw2[j * 4 + 0], o0);
            o1 = fmaf(a, s_lw2[j * 4 + 1], o1);
            o2 = fmaf(a, s_lw2[j * 4 + 2], o2);
            o3 = fmaf(a, s_lw2[j * 4 + 3], o3);
        }
    }
    o0 += __shfl_xor(o0, 1); o0 += __shfl_xor(o0, 2);
    o1 += __shfl_xor(o1, 1); o1 += __shfl_xor(o1, 2);
    o2 += __shfl_xor(o2, 1); o2 += __shfl_xor(o2, 2);
    o3 += __shfl_xor(o3, 1); o3 += __shfl_xor(o3, 2);
    if (i < N && l == 0) {
        float4 o = {o0 + s_lb2[0], o1 + s_lb2[1], o2 + s_lb2[2], o3 + s_lb2[3]};
        *(float4*)(out + (size_t)i * 4) = o;
    }
}

// ===========================================================================
// Launch
// ===========================================================================
extern "C" void kernel_launch(void* const* d_in, const int* in_sizes, int n_in,
                              void* d_out, int out_size, void* d_ws, size_t ws_size,
                              hipStream_t stream) {
    const float* x  = (const float*)d_in[0];
    const int*   ei = (const int*)d_in[1];
    const float* ea = (const float*)d_in[2];
    const int N = in_sizes[0] / 32;
    const int E = in_sizes[1] / 2;
    const int* srci = ei;
    const int* dsti = ei + E;

    const float* lw1 = (const float*)d_in[33];
    const float* lb1 = (const float*)d_in[34];
    const float* lw2 = (const float*)d_in[35];
    const float* lb2 = (const float*)d_in[36];

    const int nbins = (N + BINW - 1) >> BINSHIFT;   // 1563
    const int chunk = (E + NBLK - 1) / NBLK;        // 6250
    const int eblocks = (E + 255) / 256;

    // Workspace layout. tmp_meta now persists across all three layers
    // (read by gine_layer_bin) — no aliasing with h buffers.
    char* p = (char*)d_ws;
    int*   binstart   = (int*)p;   p += (size_t)(nbins + 1 + 3) / 4 * 16;
    int*   bincnt     = (int*)p;   p += (size_t)(nbins + 3) / 4 * 16;
    int*   histmat    = (int*)p;   p += (size_t)NBLK * nbins * 4;
    int2*  tmp_meta   = (int2*)p;  p += (size_t)E * 8;
    float* ea_sorted  = (float*)p; p += (size_t)E * 8 * 4;
    float* h1         = (float*)p; p += (size_t)N * 16 * 4;
    float* h2         = (float*)p; p += (size_t)N * 16 * 4;
    float* h3         = (float*)p; p += (size_t)N * 16 * 4;

    // ---- Contention-free bin sort (edges grouped by bin only) ----
    hist2d_kernel<<<NBLK, 256, 0, stream>>>(dsti, histmat, E, nbins, chunk);
    colsum_kernel<<<(nbins + 255) / 256, 256, 0, stream>>>(histmat, bincnt, nbins);
    bin_scan_kernel<<<1, 1024, 0, stream>>>(bincnt, binstart, nbins, E);
    rowscan_kernel<<<nbins, NBLK, 0, stream>>>(histmat, binstart, nbins);
    place_kernel<<<NBLK, 256, 0, stream>>>(srci, dsti, histmat, tmp_meta,
                                           E, nbins, chunk);
    permute_ea_kernel<<<eblocks, 256, 0, stream>>>(ea, tmp_meta, ea_sorted, E);

    // ---- Layers (edge-parallel per bin) ----
    gine_layer_bin<32, 8><<<nbins, 256, 0, stream>>>(
        x, binstart, tmp_meta, ea_sorted,
        (const float*)d_in[3], (const float*)d_in[4],
        (const float*)d_in[5], (const float*)d_in[6],
        (const float*)d_in[7], (const float*)d_in[8],
        (const float*)d_in[9], (const float*)d_in[10],
        (const float*)d_in[11], (const float*)d_in[12], h1, N);

    gine_layer_bin<16, 4><<<nbins, 256, 0, stream>>>(
        h1, binstart, tmp_meta, ea_sorted,
        (const float*)d_in[13], (const float*)d_in[14],
        (const float*)d_in[15], (const float*)d_in[16],
        (const float*)d_in[17], (const float*)d_in[18],
        (const float*)d_in[19], (const float*)d_in[20],
        (const float*)d_in[21], (const float*)d_in[22], h2, N);

    gine_layer_bin<16, 4><<<nbins, 256, 0, stream>>>(
        h2, binstart, tmp_meta, ea_sorted,
        (const float*)d_in[23], (const float*)d_in[24],
        (const float*)d_in[25], (const float*)d_in[26],
        (const float*)d_in[27], (const float*)d_in[28],
        (const float*)d_in[29], (const float*)d_in[30],
        (const float*)d_in[31], (const float*)d_in[32], h3, N);

    // ---- Head ----
    final_kernel<<<(N + 63) / 64, 256, 0, stream>>>(
        h1, h2, h3, lw1, lb1, lw2, lb2, (float*)d_out, N);
}

// Round 7
// 503.428 us; speedup vs baseline: 1.8173x; 1.8173x over previous
//
#include <hip/hip_runtime.h>
#include <hip/hip_bf16.h>

#define BN_EPS 1e-5f
#define BINSHIFT 6
#define BINW 64
#define NBLK 256   // chunks for the contention-free counting sort

// ===========================================================================
// Preprocessing (identical to round 5): contention-free counting sort by
// bin = dst>>6, then per-bin fine sort to node granularity + ea permute.
// ===========================================================================

__global__ __launch_bounds__(256)
void hist2d_kernel(const int* __restrict__ dst, int* __restrict__ histmat,
                   int E, int nbins, int chunk) {
    __shared__ int h[2048];
    for (int i = threadIdx.x; i < nbins; i += 256) h[i] = 0;
    __syncthreads();
    int b = blockIdx.x;
    int e0 = b * chunk;
    int e1 = min(E, e0 + chunk);
    for (int e = e0 + threadIdx.x; e < e1; e += 256)
        atomicAdd(&h[dst[e] >> BINSHIFT], 1);
    __syncthreads();
    int* row = histmat + (size_t)b * nbins;
    for (int i = threadIdx.x; i < nbins; i += 256) row[i] = h[i];
}

__global__ __launch_bounds__(256)
void colsum_kernel(const int* __restrict__ histmat, int* __restrict__ bincnt,
                   int nbins) {
    int bin = blockIdx.x * 256 + threadIdx.x;
    if (bin >= nbins) return;
    int s = 0;
    for (int r = 0; r < NBLK; ++r) s += histmat[(size_t)r * nbins + bin];
    bincnt[bin] = s;
}

__global__ __launch_bounds__(1024)
void bin_scan_kernel(const int* __restrict__ bincnt, int* __restrict__ binstart,
                     int nbins, int E) {
    __shared__ int a[2048];
    __shared__ int b[1024];
    int t = threadIdx.x;
    a[t]        = (t < nbins) ? bincnt[t] : 0;
    a[t + 1024] = (t + 1024 < nbins) ? bincnt[t + 1024] : 0;
    __syncthreads();
    b[t] = a[2 * t] + a[2 * t + 1];
    __syncthreads();
    for (int off = 1; off < 1024; off <<= 1) {
        int v = (t >= off) ? b[t - off] : 0;
        __syncthreads();
        b[t] += v;
        __syncthreads();
    }
    int base = (t == 0) ? 0 : b[t - 1];
    if (2 * t < nbins)     binstart[2 * t]     = base;
    if (2 * t + 1 < nbins) binstart[2 * t + 1] = base + a[2 * t];
    if (t == 0) binstart[nbins] = E;
}

__global__ __launch_bounds__(256)
void rowscan_kernel(int* __restrict__ histmat, const int* __restrict__ binstart,
                    int nbins) {
    __shared__ int a[NBLK];
    int b = blockIdx.x;
    int t = threadIdx.x;
    int v = histmat[(size_t)t * nbins + b];
    a[t] = v;
    __syncthreads();
    for (int off = 1; off < NBLK; off <<= 1) {
        int add = (t >= off) ? a[t - off] : 0;
        __syncthreads();
        a[t] += add;
        __syncthreads();
    }
    histmat[(size_t)t * nbins + b] = binstart[b] + a[t] - v;
}

__global__ __launch_bounds__(256)
void place_kernel(const int* __restrict__ src, const int* __restrict__ dst,
                  const int* __restrict__ histmat, int2* __restrict__ tmp_meta,
                  int E, int nbins, int chunk) {
    __shared__ int cur[2048];
    int b = blockIdx.x;
    const int* row = histmat + (size_t)b * nbins;
    for (int i = threadIdx.x; i < nbins; i += 256) cur[i] = row[i];
    __syncthreads();
    int e0 = b * chunk;
    int e1 = min(E, e0 + chunk);
    for (int e = e0 + threadIdx.x; e < e1; e += 256) {
        int d = dst[e];
        int bin = d >> BINSHIFT;
        int pos = atomicAdd(&cur[bin], 1);   // LDS atomic (few per thread — fine)
        int2 m;
        m.x = ((d & (BINW - 1)) << 20) | src[e];  // src < 2^20
        m.y = e;
        tmp_meta[pos] = m;
    }
}

__global__ __launch_bounds__(256)
void pass2_kernel(const int* __restrict__ binstart, const int2* __restrict__ tmp_meta,
                  const float* __restrict__ edge_attr,
                  int* __restrict__ rowstart, int* __restrict__ src_sorted,
                  float* __restrict__ ea_sorted, int N, int E, int nbins) {
    __shared__ int s_cur[BINW];
    int b = blockIdx.x;
    int node0 = b << BINSHIFT;
    int e0 = binstart[b], e1 = binstart[b + 1];
    int t = threadIdx.x;

    if (t < BINW) s_cur[t] = 0;
    __syncthreads();

    for (int e = e0 + t; e < e1; e += 256)
        atomicAdd(&s_cur[tmp_meta[e].x >> 20], 1);
    __syncthreads();

    if (t < BINW) {
        int val = s_cur[t];
        int inc = val;
#pragma unroll
        for (int off = 1; off < 64; off <<= 1) {
            int n = __shfl_up(inc, off);
            if (t >= off) inc += n;
        }
        int excl = e0 + inc - val;
        s_cur[t] = excl;
        int node = node0 + t;
        if (node <= N) rowstart[node] = excl;
    }
    __syncthreads();

    for (int e = e0 + t; e < e1; e += 256) {
        int2 m = tmp_meta[e];
        int dl   = m.x >> 20;
        int srcv = m.x & 0xFFFFF;
        int eid  = m.y;
        int fpos = atomicAdd(&s_cur[dl], 1);
        src_sorted[fpos] = srcv;
        const float4* sp = (const float4*)(edge_attr + (size_t)eid * 8);
        float4 a0 = sp[0], a1 = sp[1];
        float4* dp = (float4*)(ea_sorted + (size_t)fpos * 8);
        dp[0] = a0;
        dp[1] = a1;
    }
}

// ===========================================================================
// Fused GINE layer — WAVE PER NODE, edge-parallel slots.
// Lane = c*S + s: S edge-slots × C channel-groups (C*4 = DIN, C*S = 64).
// Slot s handles edges e0+s, e0+s+S, ... (parallel load chains, no
// inter-node divergence). Register accumulate, shfl_xor butterfly reduce
// over slot bits, no atomics. Each wave does 4 nodes serially; block =
// 4 waves = 16 nodes; epilogue: 256 threads = 16 nodes x 16 outputs,
// fully coalesced 1 KB store.
// ===========================================================================
template<int DIN, int C, int S>
__global__ __launch_bounds__(256)
void gine_layer_wave(const float* __restrict__ xin,        // [N, DIN]
                     const int*   __restrict__ rowstart,   // [N+1]
                     const int*   __restrict__ src_sorted, // [E]
                     const float* __restrict__ ea_sorted,  // [E, 8]
                     const float* __restrict__ ew, const float* __restrict__ eb,
                     const float* __restrict__ wa, const float* __restrict__ ba,
                     const float* __restrict__ g, const float* __restrict__ be,
                     const float* __restrict__ m, const float* __restrict__ v,
                     const float* __restrict__ wb, const float* __restrict__ bb,
                     float* __restrict__ hout,             // [N, 16]
                     int N) {
    static_assert(C * S == 64 && C * 4 == DIN, "lane layout");
    constexpr int PAD = DIN + 1;

    __shared__ float s_wa[DIN * 16];
    __shared__ float s_wb[256];
    __shared__ float s_ba[16], s_scale[16], s_shift[16], s_bb[16];
    __shared__ float s_s[16 * PAD];
    __shared__ float s_h[16 * 17];

    int t = threadIdx.x;
    for (int idx = t; idx < DIN * 16; idx += 256) s_wa[idx] = wa[idx];
    s_wb[t] = wb[t];
    if (t < 16) {
        s_ba[t] = ba[t];
        float sc = g[t] * rsqrtf(v[t] + BN_EPS);
        s_scale[t] = sc;
        s_shift[t] = be[t] - m[t] * sc;
        s_bb[t] = bb[t];
    }

    int w    = t >> 6;        // wave id (0..3)
    int lane = t & 63;
    int c    = lane / S;      // channel group
    int s    = lane % S;      // edge slot
    int c0   = c * 4;

    // hoist this channel-group's ew columns + eb
    float ew_r[8][4];
#pragma unroll
    for (int k = 0; k < 8; ++k) {
        float4 wv = *(const float4*)(ew + k * DIN + c0);
        ew_r[k][0] = wv.x; ew_r[k][1] = wv.y; ew_r[k][2] = wv.z; ew_r[k][3] = wv.w;
    }
    float4 ebv = *(const float4*)(eb + c0);
    float eb_r[4] = {ebv.x, ebv.y, ebv.z, ebv.w};

    int node0 = blockIdx.x * 16;

#pragma unroll
    for (int q = 0; q < 4; ++q) {
        int nl = w * 4 + q;
        int i  = node0 + nl;
        float acc[4] = {0.f, 0.f, 0.f, 0.f};
        if (i < N) {
            int e0 = rowstart[i];
            int e1 = rowstart[i + 1];
            for (int e = e0 + s; e < e1; e += S) {
                int sv = src_sorted[e];
                const float4* ep = (const float4*)(ea_sorted + (size_t)e * 8);
                float4 a0 = ep[0], a1 = ep[1];
                float4 xv = *(const float4*)(xin + (size_t)sv * DIN + c0);
                float av[8] = {a0.x, a0.y, a0.z, a0.w, a1.x, a1.y, a1.z, a1.w};
                float xr[4] = {xv.x, xv.y, xv.z, xv.w};
#pragma unroll
                for (int j = 0; j < 4; ++j) {
                    float lin = eb_r[j];
#pragma unroll
                    for (int k = 0; k < 8; ++k) lin = fmaf(av[k], ew_r[k][j], lin);
                    lin += xr[j];
                    acc[j] += (lin > 0.f ? lin : 0.f);
                }
            }
        }
        // butterfly reduce across slot bits (all lanes participate)
#pragma unroll
        for (int mask = S >> 1; mask >= 1; mask >>= 1) {
#pragma unroll
            for (int j = 0; j < 4; ++j) acc[j] += __shfl_xor(acc[j], mask);
        }
        if (s == 0 && i < N) {
            float4 xi = *(const float4*)(xin + (size_t)i * DIN + c0);
            s_s[nl * PAD + c0 + 0] = acc[0] + xi.x;
            s_s[nl * PAD + c0 + 1] = acc[1] + xi.y;
            s_s[nl * PAD + c0 + 2] = acc[2] + xi.z;
            s_s[nl * PAD + c0 + 3] = acc[3] + xi.w;
        }
    }
    __syncthreads();

    // node transform: thread t -> node t/16, output t%16
    int nl2 = t >> 4;
    int j   = t & 15;
    float a = s_ba[j];
#pragma unroll
    for (int k = 0; k < DIN; ++k)
        a = fmaf(s_s[nl2 * PAD + k], s_wa[k * 16 + j], a);
    a = a * s_scale[j] + s_shift[j];
    s_h[nl2 * 17 + j] = a > 0.f ? a : 0.f;
    __syncthreads();

    float o = s_bb[j];
#pragma unroll
    for (int k = 0; k < 16; ++k)
        o = fmaf(s_h[nl2 * 17 + k], s_wb[k * 16 + j], o);
    o = o > 0.f ? o : 0.f;
    int i2 = node0 + nl2;
    if (i2 < N) hout[(size_t)i2 * 16 + j] = o;   // = hout[node0*16 + t]: coalesced
}

// ===========================================================================
// Head (unchanged)
// ===========================================================================
__global__ __launch_bounds__(256)
void final_kernel(const float* __restrict__ h1, const float* __restrict__ h2,
                  const float* __restrict__ h3,
                  const float* __restrict__ lw1, const float* __restrict__ lb1,
                  const float* __restrict__ lw2, const float* __restrict__ lb2,
                  float* __restrict__ out, int N) {
    constexpr int NPB = 64;
    __shared__ float s_lw1[48 * 64];
    __shared__ float s_lw2[64 * 4];
    __shared__ float s_lb1[64];
    __shared__ float s_lb2[4];
    __shared__ float s_c[NPB][49];

    int t = threadIdx.x;
    for (int idx = t; idx < 48 * 64; idx += 256) s_lw1[idx] = lw1[idx];
    s_lw2[t] = lw2[t];
    if (t < 64) s_lb1[t] = lb1[t];
    if (t < 4) s_lb2[t] = lb2[t];

    int nl = t >> 2;
    int l  = t & 3;
    int i  = blockIdx.x * NPB + nl;

    if (i < N) {
        float4 c1 = ((const float4*)(h1 + (size_t)i * 16))[l];
        float4 c2 = ((const float4*)(h2 + (size_t)i * 16))[l];
        float4 c3 = ((const float4*)(h3 + (size_t)i * 16))[l];
        s_c[nl][l * 4 + 0] = c1.x; s_c[nl][l * 4 + 1] = c1.y;
        s_c[nl][l * 4 + 2] = c1.z; s_c[nl][l * 4 + 3] = c1.w;
        s_c[nl][16 + l * 4 + 0] = c2.x; s_c[nl][16 + l * 4 + 1] = c2.y;
        s_c[nl][16 + l * 4 + 2] = c2.z; s_c[nl][16 + l * 4 + 3] = c2.w;
        s_c[nl][32 + l * 4 + 0] = c3.x; s_c[nl][32 + l * 4 + 1] = c3.y;
        s_c[nl][32 + l * 4 + 2] = c3.z; s_c[nl][32 + l * 4 + 3] = c3.w;
    }
    __syncthreads();

    float o0 = 0.f, o1 = 0.f, o2 = 0.f, o3 = 0.f;
    if (i < N) {
#pragma unroll 4
        for (int jj = 0; jj < 16; ++jj) {
            int j = l * 16 + jj;
            float a = s_lb1[j];
#pragma unroll
            for (int k = 0; k < 48; ++k) a = fmaf(s_c[nl][k], s_lw1[k * 64 + j], a);
            a = a > 0.f ? a : 0.f;
            o0 = fmaf(a, s_lw2[j * 4 + 0], o0);
            o1 = fmaf(a, s_lw2[j * 4 + 1], o1);
            o2 = fmaf(a, s_lw2[j * 4 + 2], o2);
            o3 = fmaf(a, s_lw2[j * 4 + 3], o3);
        }
    }
    o0 += __shfl_xor(o0, 1); o0 += __shfl_xor(o0, 2);
    o1 += __shfl_xor(o1, 1); o1 += __shfl_xor(o1, 2);
    o2 += __shfl_xor(o2, 1); o2 += __shfl_xor(o2, 2);
    o3 += __shfl_xor(o3, 1); o3 += __shfl_xor(o3, 2);
    if (i < N && l == 0) {
        float4 o = {o0 + s_lb2[0], o1 + s_lb2[1], o2 + s_lb2[2], o3 + s_lb2[3]};
        *(float4*)(out + (size_t)i * 4) = o;
    }
}

// ===========================================================================
// Launch
// ===========================================================================
extern "C" void kernel_launch(void* const* d_in, const int* in_sizes, int n_in,
                              void* d_out, int out_size, void* d_ws, size_t ws_size,
                              hipStream_t stream) {
    const float* x  = (const float*)d_in[0];
    const int*   ei = (const int*)d_in[1];
    const float* ea = (const float*)d_in[2];
    const int N = in_sizes[0] / 32;
    const int E = in_sizes[1] / 2;
    const int* srci = ei;
    const int* dsti = ei + E;

    const float* lw1 = (const float*)d_in[33];
    const float* lb1 = (const float*)d_in[34];
    const float* lw2 = (const float*)d_in[35];
    const float* lb2 = (const float*)d_in[36];

    const int nbins = (N + BINW - 1) >> BINSHIFT;   // 1563
    const int chunk = (E + NBLK - 1) / NBLK;        // 6250

    // Workspace layout; tmp_meta aliases h1..h3 (dead after pass2).
    char* p = (char*)d_ws;
    int*   binstart   = (int*)p;   p += (size_t)(nbins + 1 + 3) / 4 * 16;
    int*   bincnt     = (int*)p;   p += (size_t)(nbins + 3) / 4 * 16;
    int*   rowstart   = (int*)p;   p += (size_t)(N + 1 + 3) / 4 * 16;
    int*   histmat    = (int*)p;   p += (size_t)NBLK * nbins * 4;
    int*   src_sorted = (int*)p;   p += (size_t)E * 4;
    float* ea_sorted  = (float*)p; p += (size_t)E * 8 * 4;
    char*  u          = p;
    int2*  tmp_meta   = (int2*)u;
    float* h1         = (float*)u;
    float* h2         = h1 + (size_t)N * 16;
    float* h3         = h2 + (size_t)N * 16;

    // ---- Contention-free bin sort + per-bin fine sort ----
    hist2d_kernel<<<NBLK, 256, 0, stream>>>(dsti, histmat, E, nbins, chunk);
    colsum_kernel<<<(nbins + 255) / 256, 256, 0, stream>>>(histmat, bincnt, nbins);
    bin_scan_kernel<<<1, 1024, 0, stream>>>(bincnt, binstart, nbins, E);
    rowscan_kernel<<<nbins, NBLK, 0, stream>>>(histmat, binstart, nbins);
    place_kernel<<<NBLK, 256, 0, stream>>>(srci, dsti, histmat, tmp_meta,
                                           E, nbins, chunk);
    pass2_kernel<<<nbins, 256, 0, stream>>>(binstart, tmp_meta, ea,
                                            rowstart, src_sorted, ea_sorted,
                                            N, E, nbins);

    // ---- Layers (wave-per-node, edge-parallel) ----
    const int lblocks = (N + 15) / 16;
    gine_layer_wave<32, 8, 8><<<lblocks, 256, 0, stream>>>(
        x, rowstart, src_sorted, ea_sorted,
        (const float*)d_in[3], (const float*)d_in[4],
        (const float*)d_in[5], (const float*)d_in[6],
        (const float*)d_in[7], (const float*)d_in[8],
        (const float*)d_in[9], (const float*)d_in[10],
        (const float*)d_in[11], (const float*)d_in[12], h1, N);

    gine_layer_wave<16, 4, 16><<<lblocks, 256, 0, stream>>>(
        h1, rowstart, src_sorted, ea_sorted,
        (const float*)d_in[13], (const float*)d_in[14],
        (const float*)d_in[15], (const float*)d_in[16],
        (const float*)d_in[17], (const float*)d_in[18],
        (const float*)d_in[19], (const float*)d_in[20],
        (const float*)d_in[21], (const float*)d_in[22], h2, N);

    gine_layer_wave<16, 4, 16><<<lblocks, 256, 0, stream>>>(
        h2, rowstart, src_sorted, ea_sorted,
        (const float*)d_in[23], (const float*)d_in[24],
        (const float*)d_in[25], (const float*)d_in[26],
        (const float*)d_in[27], (const float*)d_in[28],
        (const float*)d_in[29], (const float*)d_in[30],
        (const float*)d_in[31], (const float*)d_in[32], h3, N);

    // ---- Head ----
    final_kernel<<<(N + 63) / 64, 256, 0, stream>>>(
        h1, h2, h3, lw1, lb1, lw2, lb2, (float*)d_out, N);
}